// Round 8
// baseline (300.860 us; speedup 1.0000x reference)
//
#include <hip/hip_runtime.h>

#define NS   125      // n_support
#define NW   5        // n_way
#define NQ   2048
#define DD   8192
#define CREG 0.1f
#define PGD_ITERS 12

// ws float offsets
#define OFF_PART 0          // 64 * 15625 = 1,000,000 floats
#define OFF_K    1000000    // 15625
#define OFF_QP3  1016000    // 625
#define OFF_W    1017000    // 5*8192 = 40960
#define OFF_LP   1060000    // logits partials: 4 * NQ * NW = 40960 floats
#define OFF_CNT  1101000    // 256 int counters (zeroed by gram_partial)

// ---------------- Gram partials: block = (d-chunk c, quadrant qy, qz) ----------------
__global__ __launch_bounds__(256) void gram_partial(const float* __restrict__ support,
                                                    float* __restrict__ part,
                                                    int* __restrict__ counters) {
    __shared__ __align__(16) float As[128][68];  // [d][s-local], pitch 68 (2-way reads = free)
    __shared__ __align__(16) float Bs[128][68];
    const int tid = threadIdx.x;
    const int c  = blockIdx.x;
    const int qy = blockIdx.y, qz = blockIdx.z;
    // zero the logits counters for the fused finisher (stream order guarantees visibility)
    if (qy == 0 && qz == 0 && tid < 4) counters[c * 4 + tid] = 0;
    const int d0 = c * 128;
    const int sy0 = qy * 64, sz0 = qz * 64;
    for (int idx = tid; idx < 64 * 128; idx += 256) {
        int sl = idx >> 7, dj = idx & 127;
        int sa = sy0 + sl, sb = sz0 + sl;
        As[dj][sl] = (sa < NS) ? support[(size_t)sa * DD + d0 + dj] : 0.f;
        Bs[dj][sl] = (sb < NS) ? support[(size_t)sb * DD + d0 + dj] : 0.f;
    }
    __syncthreads();
    const int tx = tid & 15, ty = tid >> 4;   // 4x4 tile
    float acc[4][4];
#pragma unroll
    for (int i = 0; i < 4; i++)
#pragma unroll
        for (int j = 0; j < 4; j++) acc[i][j] = 0.f;
#pragma unroll 4
    for (int d = 0; d < 128; ++d) {
        float4 a = *(const float4*)&As[d][tx * 4];
        float4 b = *(const float4*)&Bs[d][ty * 4];
        float av[4] = {a.x, a.y, a.z, a.w};
        float bv[4] = {b.x, b.y, b.z, b.w};
#pragma unroll
        for (int i = 0; i < 4; i++)
#pragma unroll
            for (int j = 0; j < 4; j++) acc[i][j] += av[i] * bv[j];
    }
    float* dst = part + (size_t)c * (NS * NS);
#pragma unroll
    for (int i = 0; i < 4; i++) {
        int gi = sy0 + tx * 4 + i;
        if (gi >= NS) continue;
#pragma unroll
        for (int j = 0; j < 4; j++) {
            int gj = sz0 + ty * 4 + j;
            if (gj < NS) dst[gi * NS + gj] = acc[i][j];
        }
    }
}

// ---------------- Reduce partials -> K ----------------
__global__ __launch_bounds__(256) void gram_reduce(const float* __restrict__ part,
                                                   float* __restrict__ Kg) {
    int t = blockIdx.x * 256 + threadIdx.x;
    if (t < NS * NS) {
        float s = 0.f;
        for (int c = 0; c < 64; ++c) s += part[(size_t)c * (NS * NS) + t];
        Kg[t] = s;
    }
}

// ---------------- QP via PGD — R4 structure (proven 1.96 us/iter), 12 iters ----------
__global__ __launch_bounds__(256) void qp_solve(const float* __restrict__ Kg,
                                                const int* __restrict__ labels,
                                                float* __restrict__ qp3,
                                                float* __restrict__ outNumSv) {
    __shared__ __align__(16) float zs[NW][128];   // z columns (rows 125..127 stay 0)
    __shared__ float red2[128 * 25];
    __shared__ float rsmax[2];
    __shared__ int svcount;

    const int tid  = threadIdx.x;
    const int w    = tid >> 6;
    const int lane = tid & 63;
    const int c0   = w * 32;
    const int r0   = lane, r1 = lane + 64;

    float kr0[32], kr1[32];
#pragma unroll
    for (int j = 0; j < 32; ++j) {
        const int col = c0 + j;
        const bool cv = (col < NS);
        kr0[j] = cv ? Kg[col * NS + r0] : 0.f;
        kr1[j] = (cv && r1 < NS) ? Kg[col * NS + r1] : 0.f;
    }
    for (int idx = tid; idx < NW * 128; idx += 256) ((float*)zs)[idx] = 0.f;
    if (tid == 0) svcount = 0;
    float rsum0 = 0.f, rsum1 = 0.f;
#pragma unroll
    for (int j = 0; j < 32; ++j) { rsum0 += fabsf(kr0[j]); rsum1 += fabsf(kr1[j]); }
    red2[r0 * 25 + w * 5] = rsum0;
    red2[r1 * 25 + w * 5] = rsum1;
    __syncthreads();
    const int prow = w * 64 + lane;   // projector row for w<2
    if (w < 2) {
        const float* rr = &red2[prow * 25];
        float t = (prow < NS) ? rr[0] + rr[5] + rr[10] + rr[15] : 0.f;
#pragma unroll
        for (int off = 32; off; off >>= 1) t = fmaxf(t, __shfl_xor(t, off));
        if (lane == 0) rsmax[w] = t;
    }
    __syncthreads();
    const float eta = 1.9f / (fmaxf(rsmax[0], rsmax[1]) + 1.0f);  // G = kron(K,I5)+I
    const int lab = (w < 2 && prow < NS) ? labels[prow] : 0;
    float z[NW] = {0.f, 0.f, 0.f, 0.f, 0.f};

    for (int it = 0; it < PGD_ITERS; ++it) {
        float acc0[NW] = {0.f, 0.f, 0.f, 0.f, 0.f};
        float acc1[NW] = {0.f, 0.f, 0.f, 0.f, 0.f};
#pragma unroll
        for (int c = 0; c < 8; ++c) {
            const int jb = c0 + 4 * c;                 // wave-uniform -> broadcast b128
            float4 z0 = *(const float4*)&zs[0][jb];
            float4 z1 = *(const float4*)&zs[1][jb];
            float4 z2 = *(const float4*)&zs[2][jb];
            float4 z3 = *(const float4*)&zs[3][jb];
            float4 z4 = *(const float4*)&zs[4][jb];
            const float k00 = kr0[4*c], k01 = kr0[4*c+1], k02 = kr0[4*c+2], k03 = kr0[4*c+3];
            const float k10 = kr1[4*c], k11 = kr1[4*c+1], k12 = kr1[4*c+2], k13 = kr1[4*c+3];
            acc0[0] += k00*z0.x + k01*z0.y + k02*z0.z + k03*z0.w;
            acc0[1] += k00*z1.x + k01*z1.y + k02*z1.z + k03*z1.w;
            acc0[2] += k00*z2.x + k01*z2.y + k02*z2.z + k03*z2.w;
            acc0[3] += k00*z3.x + k01*z3.y + k02*z3.z + k03*z3.w;
            acc0[4] += k00*z4.x + k01*z4.y + k02*z4.z + k03*z4.w;
            acc1[0] += k10*z0.x + k11*z0.y + k12*z0.z + k13*z0.w;
            acc1[1] += k10*z1.x + k11*z1.y + k12*z1.z + k13*z1.w;
            acc1[2] += k10*z2.x + k11*z2.y + k12*z2.z + k13*z2.w;
            acc1[3] += k10*z3.x + k11*z3.y + k12*z3.z + k13*z3.w;
            acc1[4] += k10*z4.x + k11*z4.y + k12*z4.z + k13*z4.w;
        }
        {
            float* b0 = &red2[r0 * 25 + w * 5];
            b0[0] = acc0[0]; b0[1] = acc0[1]; b0[2] = acc0[2]; b0[3] = acc0[3]; b0[4] = acc0[4];
            float* b1 = &red2[r1 * 25 + w * 5];
            b1[0] = acc1[0]; b1[1] = acc1[1]; b1[2] = acc1[2]; b1[3] = acc1[3]; b1[4] = acc1[4];
        }
        __syncthreads();
        if (w < 2 && prow < NS) {
            const float* rr = &red2[prow * 25];
            float v[NW], h[NW];
#pragma unroll
            for (int a = 0; a < NW; a++) {
                float kz = rr[a] + rr[5 + a] + rr[10 + a] + rr[15 + a];
                float g = kz + z[a] - ((a == lab) ? 1.f : 0.f);   // Gz + e
                v[a] = z[a] - eta * g;
                h[a] = (a == lab) ? CREG : 0.f;
            }
            float tau = fmaxf(fmaxf(fmaxf(v[0], v[1]), fmaxf(v[2], v[3])), v[4]);
#pragma unroll
            for (int n = 0; n < 7; ++n) {
                float g = 0.f, nf = 0.f;
#pragma unroll
                for (int a = 0; a < NW; a++) {
                    float d = v[a] - tau;
                    bool fr = (d <= h[a]);
                    g += fr ? d : h[a];
                    nf += fr ? 1.f : 0.f;
                }
                tau += g / nf;
            }
#pragma unroll
            for (int a = 0; a < NW; a++) {
                z[a] = fminf(v[a] - tau, h[a]);
                zs[a][prow] = z[a];
            }
        }
        __syncthreads();
    }

    if (w < 2 && prow < NS) {
        float m = fmaxf(fmaxf(fmaxf(z[0], z[1]), fmaxf(z[2], z[3])), z[4]);
        if (m > 0.001f) atomicAdd(&svcount, 1);
#pragma unroll
        for (int a = 0; a < NW; a++) qp3[prow * NW + a] = z[a];
    }
    __syncthreads();
    if (tid == 0) *outNumSv = (float)svcount;
}

// ---------------- W[a][d] = sum_s support[s][d] * qp3[s][a] ----------------
// 4-way s-split for ILP: wave sq covers s in [32sq, min(32sq+32,125)); LDS combine.
__global__ __launch_bounds__(256) void w_kernel(const float* __restrict__ support,
                                                const float* __restrict__ qp3,
                                                float* __restrict__ W) {
    __shared__ float q3[NS * NW];
    __shared__ float red[4 * 64 * NW];
    const int tid = threadIdx.x;
    for (int i = tid; i < NS * NW; i += 256) q3[i] = qp3[i];
    __syncthreads();
    const int ld = tid & 63;            // local d
    const int sq = tid >> 6;            // s-quarter (wave-uniform)
    const int d  = blockIdx.x * 64 + ld;
    const int s0 = sq * 32;
    const int s1 = (sq == 3) ? NS : (s0 + 32);
    float acc[NW] = {0.f, 0.f, 0.f, 0.f, 0.f};
#pragma unroll 4
    for (int s = s0; s < s1; ++s) {
        float sv = support[(size_t)s * DD + d];
#pragma unroll
        for (int a = 0; a < NW; a++) acc[a] += sv * q3[s * NW + a];
    }
    float* rr = &red[tid * NW];
#pragma unroll
    for (int a = 0; a < NW; a++) rr[a] = acc[a];
    __syncthreads();
    if (sq == 0) {
#pragma unroll
        for (int a = 0; a < NW; a++) {
            float s = red[(0 * 64 + ld) * NW + a] + red[(1 * 64 + ld) * NW + a]
                    + red[(2 * 64 + ld) * NW + a] + red[(3 * 64 + ld) * NW + a];
            W[(size_t)a * DD + d] = s;
        }
    }
}

// ---------------- logits fused: partials + last-block finish --------------------
// grid (NQ/8, 4 d-chunks). Each block: 2 q/wave over its 512-float4 chunk -> lp.
// Last-arriving block per q-group (device-scope counter) sums 4 chunks * scale -> out.
__global__ __launch_bounds__(256) void logits_fused(const float* __restrict__ query,
                                                    const float* __restrict__ W,
                                                    const float* __restrict__ scale,
                                                    float* __restrict__ lp,
                                                    int* __restrict__ counters,
                                                    float* __restrict__ out) {
    __shared__ int is_last;
    const int tid = threadIdx.x;
    const int wave = tid >> 6, lane = tid & 63;
    const int bx = blockIdx.x;
    const int q0 = bx * 8 + wave * 2;
    const int q1 = q0 + 1;
    const int chunk = blockIdx.y;
    const int v0 = chunk * 512;            // float4 base (512 float4 = 2048 floats)
    float a0[NW] = {0.f, 0.f, 0.f, 0.f, 0.f};
    float a1[NW] = {0.f, 0.f, 0.f, 0.f, 0.f};
    const float4* qp0 = (const float4*)(query + (size_t)q0 * DD);
    const float4* qp1 = (const float4*)(query + (size_t)q1 * DD);
#pragma unroll 2
    for (int it = 0; it < 8; ++it) {
        int dv = v0 + it * 64 + lane;
        float4 qv0 = qp0[dv];
        float4 qv1 = qp1[dv];
#pragma unroll
        for (int a = 0; a < NW; a++) {
            float4 wv = ((const float4*)(W + (size_t)a * DD))[dv];
            a0[a] += qv0.x * wv.x + qv0.y * wv.y + qv0.z * wv.z + qv0.w * wv.w;
            a1[a] += qv1.x * wv.x + qv1.y * wv.y + qv1.z * wv.z + qv1.w * wv.w;
        }
    }
#pragma unroll
    for (int off = 32; off; off >>= 1) {
#pragma unroll
        for (int a = 0; a < NW; a++) {
            a0[a] += __shfl_xor(a0[a], off);
            a1[a] += __shfl_xor(a1[a], off);
        }
    }
    if (lane == 0) {
        float* dst = lp + (size_t)chunk * (NQ * NW);
#pragma unroll
        for (int a = 0; a < NW; a++) dst[q0 * NW + a] = a0[a];
#pragma unroll
        for (int a = 0; a < NW; a++) dst[q1 * NW + a] = a1[a];
        __threadfence();                 // release this wave's partials device-wide
    }
    __syncthreads();                     // all waves' stores complete (vmcnt drained)
    if (tid == 0) {
        int old = atomicAdd(&counters[bx], 1);   // device-scope
        is_last = (old == 3);
    }
    __syncthreads();
    if (is_last) {
        __threadfence();                 // acquire other blocks' partials
        if (tid < 40) {
            int ql = tid / 5, a = tid % 5;
            int q = bx * 8 + ql;
            int idx = q * NW + a;
            float s = lp[idx] + lp[NQ * NW + idx] + lp[2 * NQ * NW + idx] + lp[3 * NQ * NW + idx];
            out[idx] = scale[0] * s;
        }
    }
}

extern "C" void kernel_launch(void* const* d_in, const int* in_sizes, int n_in,
                              void* d_out, int out_size, void* d_ws, size_t ws_size,
                              hipStream_t stream) {
    const float* query   = (const float*)d_in[0];
    const float* support = (const float*)d_in[1];
    const int*   labels  = (const int*)d_in[2];
    const float* scale   = (const float*)d_in[5];
    float* out = (float*)d_out;
    float* ws  = (float*)d_ws;

    float* part = ws + OFF_PART;
    float* Kg   = ws + OFF_K;
    float* qp3  = ws + OFF_QP3;
    float* W    = ws + OFF_W;
    float* lp   = ws + OFF_LP;
    int*   cnt  = (int*)(ws + OFF_CNT);

    hipLaunchKernelGGL(gram_partial, dim3(64, 2, 2), dim3(256), 0, stream, support, part, cnt);
    hipLaunchKernelGGL(gram_reduce, dim3(62), dim3(256), 0, stream, part, Kg);
    hipLaunchKernelGGL(qp_solve, dim3(1), dim3(256), 0, stream, Kg, labels, qp3, out + NQ * NW);
    hipLaunchKernelGGL(w_kernel, dim3(DD / 64), dim3(256), 0, stream, support, qp3, W);
    hipLaunchKernelGGL(logits_fused, dim3(NQ / 8, 4), dim3(256), 0, stream, query, W, scale, lp, cnt, out);
}

// Round 9
// 169.357 us; speedup vs baseline: 1.7765x; 1.7765x over previous
//
#include <hip/hip_runtime.h>

#define NS   125      // n_support
#define NW   5        // n_way
#define NQ   2048
#define DD   8192
#define CREG 0.1f
#define PGD_ITERS 12

// ws float offsets
#define OFF_PART 0          // 64 * 15625 = 1,000,000 floats
#define OFF_K    1000000    // 15625
#define OFF_QP3  1016000    // 625
#define OFF_W    1017000    // 5*8192 = 40960
#define OFF_LP   1060000    // logits partials: 4 * NQ * NW = 40960 floats

// ---------------- Gram partials: block = (d-chunk c, quadrant qy, qz) ----------------
__global__ __launch_bounds__(256) void gram_partial(const float* __restrict__ support,
                                                    float* __restrict__ part) {
    __shared__ __align__(16) float As[128][68];  // [d][s-local], pitch 68 (2-way reads = free)
    __shared__ __align__(16) float Bs[128][68];
    const int tid = threadIdx.x;
    const int c  = blockIdx.x;
    const int qy = blockIdx.y, qz = blockIdx.z;
    const int d0 = c * 128;
    const int sy0 = qy * 64, sz0 = qz * 64;
    for (int idx = tid; idx < 64 * 128; idx += 256) {
        int sl = idx >> 7, dj = idx & 127;
        int sa = sy0 + sl, sb = sz0 + sl;
        As[dj][sl] = (sa < NS) ? support[(size_t)sa * DD + d0 + dj] : 0.f;
        Bs[dj][sl] = (sb < NS) ? support[(size_t)sb * DD + d0 + dj] : 0.f;
    }
    __syncthreads();
    const int tx = tid & 15, ty = tid >> 4;   // 4x4 tile
    float acc[4][4];
#pragma unroll
    for (int i = 0; i < 4; i++)
#pragma unroll
        for (int j = 0; j < 4; j++) acc[i][j] = 0.f;
#pragma unroll 4
    for (int d = 0; d < 128; ++d) {
        float4 a = *(const float4*)&As[d][tx * 4];
        float4 b = *(const float4*)&Bs[d][ty * 4];
        float av[4] = {a.x, a.y, a.z, a.w};
        float bv[4] = {b.x, b.y, b.z, b.w};
#pragma unroll
        for (int i = 0; i < 4; i++)
#pragma unroll
            for (int j = 0; j < 4; j++) acc[i][j] += av[i] * bv[j];
    }
    float* dst = part + (size_t)c * (NS * NS);
#pragma unroll
    for (int i = 0; i < 4; i++) {
        int gi = sy0 + tx * 4 + i;
        if (gi >= NS) continue;
#pragma unroll
        for (int j = 0; j < 4; j++) {
            int gj = sz0 + ty * 4 + j;
            if (gj < NS) dst[gi * NS + gj] = acc[i][j];
        }
    }
}

// ---------------- Reduce partials -> K ----------------
__global__ __launch_bounds__(256) void gram_reduce(const float* __restrict__ part,
                                                   float* __restrict__ Kg) {
    int t = blockIdx.x * 256 + threadIdx.x;
    if (t < NS * NS) {
        float s = 0.f;
        for (int c = 0; c < 64; ++c) s += part[(size_t)c * (NS * NS) + t];
        Kg[t] = s;
    }
}

// ---------------- QP via PGD — R4 structure (proven 1.96 us/iter), 12 iters ----------
__global__ __launch_bounds__(256) void qp_solve(const float* __restrict__ Kg,
                                                const int* __restrict__ labels,
                                                float* __restrict__ qp3,
                                                float* __restrict__ outNumSv) {
    __shared__ __align__(16) float zs[NW][128];   // z columns (rows 125..127 stay 0)
    __shared__ float red2[128 * 25];
    __shared__ float rsmax[2];
    __shared__ int svcount;

    const int tid  = threadIdx.x;
    const int w    = tid >> 6;
    const int lane = tid & 63;
    const int c0   = w * 32;
    const int r0   = lane, r1 = lane + 64;

    float kr0[32], kr1[32];
#pragma unroll
    for (int j = 0; j < 32; ++j) {
        const int col = c0 + j;
        const bool cv = (col < NS);
        kr0[j] = cv ? Kg[col * NS + r0] : 0.f;
        kr1[j] = (cv && r1 < NS) ? Kg[col * NS + r1] : 0.f;
    }
    for (int idx = tid; idx < NW * 128; idx += 256) ((float*)zs)[idx] = 0.f;
    if (tid == 0) svcount = 0;
    float rsum0 = 0.f, rsum1 = 0.f;
#pragma unroll
    for (int j = 0; j < 32; ++j) { rsum0 += fabsf(kr0[j]); rsum1 += fabsf(kr1[j]); }
    red2[r0 * 25 + w * 5] = rsum0;
    red2[r1 * 25 + w * 5] = rsum1;
    __syncthreads();
    const int prow = w * 64 + lane;   // projector row for w<2
    if (w < 2) {
        const float* rr = &red2[prow * 25];
        float t = (prow < NS) ? rr[0] + rr[5] + rr[10] + rr[15] : 0.f;
#pragma unroll
        for (int off = 32; off; off >>= 1) t = fmaxf(t, __shfl_xor(t, off));
        if (lane == 0) rsmax[w] = t;
    }
    __syncthreads();
    const float eta = 1.9f / (fmaxf(rsmax[0], rsmax[1]) + 1.0f);  // G = kron(K,I5)+I
    const int lab = (w < 2 && prow < NS) ? labels[prow] : 0;
    float z[NW] = {0.f, 0.f, 0.f, 0.f, 0.f};

    for (int it = 0; it < PGD_ITERS; ++it) {
        float acc0[NW] = {0.f, 0.f, 0.f, 0.f, 0.f};
        float acc1[NW] = {0.f, 0.f, 0.f, 0.f, 0.f};
#pragma unroll
        for (int c = 0; c < 8; ++c) {
            const int jb = c0 + 4 * c;                 // wave-uniform -> broadcast b128
            float4 z0 = *(const float4*)&zs[0][jb];
            float4 z1 = *(const float4*)&zs[1][jb];
            float4 z2 = *(const float4*)&zs[2][jb];
            float4 z3 = *(const float4*)&zs[3][jb];
            float4 z4 = *(const float4*)&zs[4][jb];
            const float k00 = kr0[4*c], k01 = kr0[4*c+1], k02 = kr0[4*c+2], k03 = kr0[4*c+3];
            const float k10 = kr1[4*c], k11 = kr1[4*c+1], k12 = kr1[4*c+2], k13 = kr1[4*c+3];
            acc0[0] += k00*z0.x + k01*z0.y + k02*z0.z + k03*z0.w;
            acc0[1] += k00*z1.x + k01*z1.y + k02*z1.z + k03*z1.w;
            acc0[2] += k00*z2.x + k01*z2.y + k02*z2.z + k03*z2.w;
            acc0[3] += k00*z3.x + k01*z3.y + k02*z3.z + k03*z3.w;
            acc0[4] += k00*z4.x + k01*z4.y + k02*z4.z + k03*z4.w;
            acc1[0] += k10*z0.x + k11*z0.y + k12*z0.z + k13*z0.w;
            acc1[1] += k10*z1.x + k11*z1.y + k12*z1.z + k13*z1.w;
            acc1[2] += k10*z2.x + k11*z2.y + k12*z2.z + k13*z2.w;
            acc1[3] += k10*z3.x + k11*z3.y + k12*z3.z + k13*z3.w;
            acc1[4] += k10*z4.x + k11*z4.y + k12*z4.z + k13*z4.w;
        }
        {
            float* b0 = &red2[r0 * 25 + w * 5];
            b0[0] = acc0[0]; b0[1] = acc0[1]; b0[2] = acc0[2]; b0[3] = acc0[3]; b0[4] = acc0[4];
            float* b1 = &red2[r1 * 25 + w * 5];
            b1[0] = acc1[0]; b1[1] = acc1[1]; b1[2] = acc1[2]; b1[3] = acc1[3]; b1[4] = acc1[4];
        }
        __syncthreads();
        if (w < 2 && prow < NS) {
            const float* rr = &red2[prow * 25];
            float v[NW], h[NW];
#pragma unroll
            for (int a = 0; a < NW; a++) {
                float kz = rr[a] + rr[5 + a] + rr[10 + a] + rr[15 + a];
                float g = kz + z[a] - ((a == lab) ? 1.f : 0.f);   // Gz + e
                v[a] = z[a] - eta * g;
                h[a] = (a == lab) ? CREG : 0.f;
            }
            float tau = fmaxf(fmaxf(fmaxf(v[0], v[1]), fmaxf(v[2], v[3])), v[4]);
#pragma unroll
            for (int n = 0; n < 7; ++n) {
                float g = 0.f, nf = 0.f;
#pragma unroll
                for (int a = 0; a < NW; a++) {
                    float d = v[a] - tau;
                    bool fr = (d <= h[a]);
                    g += fr ? d : h[a];
                    nf += fr ? 1.f : 0.f;
                }
                tau += g / nf;
            }
#pragma unroll
            for (int a = 0; a < NW; a++) {
                z[a] = fminf(v[a] - tau, h[a]);
                zs[a][prow] = z[a];
            }
        }
        __syncthreads();
    }

    if (w < 2 && prow < NS) {
        float m = fmaxf(fmaxf(fmaxf(z[0], z[1]), fmaxf(z[2], z[3])), z[4]);
        if (m > 0.001f) atomicAdd(&svcount, 1);
#pragma unroll
        for (int a = 0; a < NW; a++) qp3[prow * NW + a] = z[a];
    }
    __syncthreads();
    if (tid == 0) *outNumSv = (float)svcount;
}

// ---------------- W[a][d] = sum_s support[s][d] * qp3[s][a] ----------------
// 4-way s-split for ILP: wave sq covers s in [32sq, min(32sq+32,125)); LDS combine.
__global__ __launch_bounds__(256) void w_kernel(const float* __restrict__ support,
                                                const float* __restrict__ qp3,
                                                float* __restrict__ W) {
    __shared__ float q3[NS * NW];
    __shared__ float red[4 * 64 * NW];
    const int tid = threadIdx.x;
    for (int i = tid; i < NS * NW; i += 256) q3[i] = qp3[i];
    __syncthreads();
    const int ld = tid & 63;            // local d
    const int sq = tid >> 6;            // s-quarter (wave-uniform)
    const int d  = blockIdx.x * 64 + ld;
    const int s0 = sq * 32;
    const int s1 = (sq == 3) ? NS : (s0 + 32);
    float acc[NW] = {0.f, 0.f, 0.f, 0.f, 0.f};
#pragma unroll 4
    for (int s = s0; s < s1; ++s) {
        float sv = support[(size_t)s * DD + d];
#pragma unroll
        for (int a = 0; a < NW; a++) acc[a] += sv * q3[s * NW + a];
    }
    float* rr = &red[tid * NW];
#pragma unroll
    for (int a = 0; a < NW; a++) rr[a] = acc[a];
    __syncthreads();
    if (sq == 0) {
#pragma unroll
        for (int a = 0; a < NW; a++) {
            float s = red[(0 * 64 + ld) * NW + a] + red[(1 * 64 + ld) * NW + a]
                    + red[(2 * 64 + ld) * NW + a] + red[(3 * 64 + ld) * NW + a];
            W[(size_t)a * DD + d] = s;
        }
    }
}

// ---------------- logits partials: grid (q-group, d-chunk); 2 q/wave over D/4 ------
__global__ __launch_bounds__(256) void logits_partial(const float* __restrict__ query,
                                                      const float* __restrict__ W,
                                                      float* __restrict__ lp) {
    const int tid = threadIdx.x;
    const int wave = tid >> 6, lane = tid & 63;
    const int q0 = blockIdx.x * 8 + wave * 2;
    const int q1 = q0 + 1;
    const int chunk = blockIdx.y;
    const int v0 = chunk * 512;            // float4 base of this chunk (512 float4 = 2048 f)
    float a0[NW] = {0.f, 0.f, 0.f, 0.f, 0.f};
    float a1[NW] = {0.f, 0.f, 0.f, 0.f, 0.f};
    const float4* qp0 = (const float4*)(query + (size_t)q0 * DD);
    const float4* qp1 = (const float4*)(query + (size_t)q1 * DD);
    for (int it = 0; it < 8; ++it) {
        int dv = v0 + it * 64 + lane;
        float4 qv0 = qp0[dv];
        float4 qv1 = qp1[dv];
#pragma unroll
        for (int a = 0; a < NW; a++) {
            float4 wv = ((const float4*)(W + (size_t)a * DD))[dv];
            a0[a] += qv0.x * wv.x + qv0.y * wv.y + qv0.z * wv.z + qv0.w * wv.w;
            a1[a] += qv1.x * wv.x + qv1.y * wv.y + qv1.z * wv.z + qv1.w * wv.w;
        }
    }
#pragma unroll
    for (int off = 32; off; off >>= 1) {
#pragma unroll
        for (int a = 0; a < NW; a++) {
            a0[a] += __shfl_xor(a0[a], off);
            a1[a] += __shfl_xor(a1[a], off);
        }
    }
    if (lane == 0) {
        float* dst = lp + (size_t)chunk * (NQ * NW);
#pragma unroll
        for (int a = 0; a < NW; a++) dst[q0 * NW + a] = a0[a];
#pragma unroll
        for (int a = 0; a < NW; a++) dst[q1 * NW + a] = a1[a];
    }
}

// ---------------- logits finish: out = scale * sum_chunks lp ----------------
__global__ __launch_bounds__(256) void logits_finish(const float* __restrict__ lp,
                                                     const float* __restrict__ scale,
                                                     float* __restrict__ out) {
    int t = blockIdx.x * 256 + threadIdx.x;
    if (t < NQ * NW) {
        float s = lp[t] + lp[NQ * NW + t] + lp[2 * NQ * NW + t] + lp[3 * NQ * NW + t];
        out[t] = scale[0] * s;
    }
}

extern "C" void kernel_launch(void* const* d_in, const int* in_sizes, int n_in,
                              void* d_out, int out_size, void* d_ws, size_t ws_size,
                              hipStream_t stream) {
    const float* query   = (const float*)d_in[0];
    const float* support = (const float*)d_in[1];
    const int*   labels  = (const int*)d_in[2];
    const float* scale   = (const float*)d_in[5];
    float* out = (float*)d_out;
    float* ws  = (float*)d_ws;

    float* part = ws + OFF_PART;
    float* Kg   = ws + OFF_K;
    float* qp3  = ws + OFF_QP3;
    float* W    = ws + OFF_W;
    float* lp   = ws + OFF_LP;

    hipLaunchKernelGGL(gram_partial, dim3(64, 2, 2), dim3(256), 0, stream, support, part);
    hipLaunchKernelGGL(gram_reduce, dim3(62), dim3(256), 0, stream, part, Kg);
    hipLaunchKernelGGL(qp_solve, dim3(1), dim3(256), 0, stream, Kg, labels, qp3, out + NQ * NW);
    hipLaunchKernelGGL(w_kernel, dim3(DD / 64), dim3(256), 0, stream, support, qp3, W);
    hipLaunchKernelGGL(logits_partial, dim3(NQ / 8, 4), dim3(256), 0, stream, query, W, lp);
    hipLaunchKernelGGL(logits_finish, dim3((NQ * NW + 255) / 256), dim3(256), 0, stream, lp, scale, out);
}

// Round 10
// 168.684 us; speedup vs baseline: 1.7836x; 1.0040x over previous
//
#include <hip/hip_runtime.h>

#define NS   125      // n_support
#define NW   5        // n_way
#define NQ   2048
#define DD   8192
#define CREG 0.1f
#define PGD_ITERS 12

// ws float offsets
#define OFF_PART 0          // 64 * 15625 = 1,000,000 floats
#define OFF_K    1000000    // 15625
#define OFF_QP3  1016000    // 625
#define OFF_W    1017000    // 5*8192 = 40960
#define OFF_LP   1060000    // logits partials: 4 * NQ * NW = 40960 floats

// ---------------- Gram partials: block = (d-chunk c, quadrant qy, qz) ----------------
__global__ __launch_bounds__(256) void gram_partial(const float* __restrict__ support,
                                                    float* __restrict__ part) {
    __shared__ __align__(16) float As[128][68];  // [d][s-local], pitch 68 (2-way reads = free)
    __shared__ __align__(16) float Bs[128][68];
    const int tid = threadIdx.x;
    const int c  = blockIdx.x;
    const int qy = blockIdx.y, qz = blockIdx.z;
    const int d0 = c * 128;
    const int sy0 = qy * 64, sz0 = qz * 64;
    for (int idx = tid; idx < 64 * 128; idx += 256) {
        int sl = idx >> 7, dj = idx & 127;
        int sa = sy0 + sl, sb = sz0 + sl;
        As[dj][sl] = (sa < NS) ? support[(size_t)sa * DD + d0 + dj] : 0.f;
        Bs[dj][sl] = (sb < NS) ? support[(size_t)sb * DD + d0 + dj] : 0.f;
    }
    __syncthreads();
    const int tx = tid & 15, ty = tid >> 4;   // 4x4 tile
    float acc[4][4];
#pragma unroll
    for (int i = 0; i < 4; i++)
#pragma unroll
        for (int j = 0; j < 4; j++) acc[i][j] = 0.f;
#pragma unroll 4
    for (int d = 0; d < 128; ++d) {
        float4 a = *(const float4*)&As[d][tx * 4];
        float4 b = *(const float4*)&Bs[d][ty * 4];
        float av[4] = {a.x, a.y, a.z, a.w};
        float bv[4] = {b.x, b.y, b.z, b.w};
#pragma unroll
        for (int i = 0; i < 4; i++)
#pragma unroll
            for (int j = 0; j < 4; j++) acc[i][j] += av[i] * bv[j];
    }
    float* dst = part + (size_t)c * (NS * NS);
#pragma unroll
    for (int i = 0; i < 4; i++) {
        int gi = sy0 + tx * 4 + i;
        if (gi >= NS) continue;
#pragma unroll
        for (int j = 0; j < 4; j++) {
            int gj = sz0 + ty * 4 + j;
            if (gj < NS) dst[gi * NS + gj] = acc[i][j];
        }
    }
}

// ---------------- Reduce partials -> K ----------------
__global__ __launch_bounds__(256) void gram_reduce(const float* __restrict__ part,
                                                   float* __restrict__ Kg) {
    int t = blockIdx.x * 256 + threadIdx.x;
    if (t < NS * NS) {
        float s = 0.f;
        for (int c = 0; c < 64; ++c) s += part[(size_t)c * (NS * NS) + t];
        Kg[t] = s;
    }
}

// ---------------- QP via PGD v3: ONE barrier/iter, wave-private z ----------------
// Wave w owns col-chunk [32w,32w+32) AND projects rows [32w,32w+32) (lanes 0-31).
// z for chunk w lives in zsw[parity][w] — written and read by wave w only (no
// barrier needed for z; compiler's lgkmcnt orders same-wave LDS). Cross-wave
// traffic = partial sums red2[parity] only, fenced by the single barrier.
// WAR on red2[p] (reused at iter k+2) is ordered by barrier k+1. Arithmetic is
// bit-identical to the R4/R9 trajectory (same chunk & projector sum order).
__global__ __launch_bounds__(256) void qp_solve(const float* __restrict__ Kg,
                                                const int* __restrict__ labels,
                                                float* __restrict__ qp3,
                                                float* __restrict__ outNumSv) {
    __shared__ float red2[2][128 * 25];             // [parity][row*25 + w*5 + a]
    __shared__ __align__(16) float zsw[2][4][NW][32];  // [parity][wave][a][j-local]
    __shared__ float rsmax[2];
    __shared__ int svcount;

    const int tid  = threadIdx.x;
    const int w    = tid >> 6;
    const int lane = tid & 63;
    const int c0   = w * 32;
    const int r0   = lane, r1 = lane + 64;

    // K row chunks via symmetry (K==K^T), coalesced
    float kr0[32], kr1[32];
#pragma unroll
    for (int j = 0; j < 32; ++j) {
        const int col = c0 + j;
        const bool cv = (col < NS);
        kr0[j] = cv ? Kg[col * NS + r0] : 0.f;
        kr1[j] = (cv && r1 < NS) ? Kg[col * NS + r1] : 0.f;
    }
    // zero both z parities (padded rows stay 0 forever)
    for (int idx = tid; idx < 2 * 4 * NW * 32; idx += 256) ((float*)zsw)[idx] = 0.f;
    if (tid == 0) svcount = 0;
    // Gershgorin row-sum partials -> eta (uses red2[0]; fenced before iter 0 reuse)
    float rsum0 = 0.f, rsum1 = 0.f;
#pragma unroll
    for (int j = 0; j < 32; ++j) { rsum0 += fabsf(kr0[j]); rsum1 += fabsf(kr1[j]); }
    red2[0][r0 * 25 + w * 5] = rsum0;
    red2[0][r1 * 25 + w * 5] = rsum1;
    __syncthreads();
    const int prw = w * 64 + lane;
    if (w < 2) {
        const float* rr = &red2[0][prw * 25];
        float t = (prw < NS) ? rr[0] + rr[5] + rr[10] + rr[15] : 0.f;
#pragma unroll
        for (int off = 32; off; off >>= 1) t = fmaxf(t, __shfl_xor(t, off));
        if (lane == 0) rsmax[w] = t;
    }
    __syncthreads();
    const float eta = 1.9f / (fmaxf(rsmax[0], rsmax[1]) + 1.0f);  // G = kron(K,I5)+I
    // projector identity: wave w, lanes 0-31 -> row pr = c0 + lane
    const int pr   = c0 + lane;
    const bool act = (lane < 32) && (pr < NS);
    const int lab  = act ? labels[pr] : 0;
    float z[NW] = {0.f, 0.f, 0.f, 0.f, 0.f};

    for (int it = 0; it < PGD_ITERS; ++it) {
        const int p = it & 1, n = p ^ 1;
        float acc0[NW] = {0.f, 0.f, 0.f, 0.f, 0.f};
        float acc1[NW] = {0.f, 0.f, 0.f, 0.f, 0.f};
#pragma unroll
        for (int c = 0; c < 8; ++c) {
            // wave-uniform addresses -> pure broadcast b128 (wave-private z strip)
            float4 z0 = *(const float4*)&zsw[p][w][0][4 * c];
            float4 z1 = *(const float4*)&zsw[p][w][1][4 * c];
            float4 z2 = *(const float4*)&zsw[p][w][2][4 * c];
            float4 z3 = *(const float4*)&zsw[p][w][3][4 * c];
            float4 z4 = *(const float4*)&zsw[p][w][4][4 * c];
            const float k00 = kr0[4*c], k01 = kr0[4*c+1], k02 = kr0[4*c+2], k03 = kr0[4*c+3];
            const float k10 = kr1[4*c], k11 = kr1[4*c+1], k12 = kr1[4*c+2], k13 = kr1[4*c+3];
            acc0[0] += k00*z0.x + k01*z0.y + k02*z0.z + k03*z0.w;
            acc0[1] += k00*z1.x + k01*z1.y + k02*z1.z + k03*z1.w;
            acc0[2] += k00*z2.x + k01*z2.y + k02*z2.z + k03*z2.w;
            acc0[3] += k00*z3.x + k01*z3.y + k02*z3.z + k03*z3.w;
            acc0[4] += k00*z4.x + k01*z4.y + k02*z4.z + k03*z4.w;
            acc1[0] += k10*z0.x + k11*z0.y + k12*z0.z + k13*z0.w;
            acc1[1] += k10*z1.x + k11*z1.y + k12*z1.z + k13*z1.w;
            acc1[2] += k10*z2.x + k11*z2.y + k12*z2.z + k13*z2.w;
            acc1[3] += k10*z3.x + k11*z3.y + k12*z3.z + k13*z3.w;
            acc1[4] += k10*z4.x + k11*z4.y + k12*z4.z + k13*z4.w;
        }
        {
            float* b0 = &red2[p][r0 * 25 + w * 5];
            b0[0] = acc0[0]; b0[1] = acc0[1]; b0[2] = acc0[2]; b0[3] = acc0[3]; b0[4] = acc0[4];
            float* b1 = &red2[p][r1 * 25 + w * 5];
            b1[0] = acc1[0]; b1[1] = acc1[1]; b1[2] = acc1[2]; b1[3] = acc1[3]; b1[4] = acc1[4];
        }
        __syncthreads();                       // the ONLY barrier per iteration
        if (act) {
            const float* rr = &red2[p][pr * 25];
            float v[NW], h[NW];
#pragma unroll
            for (int a = 0; a < NW; a++) {
                float kz = rr[a] + rr[5 + a] + rr[10 + a] + rr[15 + a];
                float g = kz + z[a] - ((a == lab) ? 1.f : 0.f);   // Gz + e
                v[a] = z[a] - eta * g;
                h[a] = (a == lab) ? CREG : 0.f;
            }
            float tau = fmaxf(fmaxf(fmaxf(v[0], v[1]), fmaxf(v[2], v[3])), v[4]);
#pragma unroll
            for (int nn = 0; nn < 7; ++nn) {
                float g = 0.f, nf = 0.f;
#pragma unroll
                for (int a = 0; a < NW; a++) {
                    float d = v[a] - tau;
                    bool fr = (d <= h[a]);
                    g += fr ? d : h[a];
                    nf += fr ? 1.f : 0.f;
                }
                tau += g / nf;
            }
#pragma unroll
            for (int a = 0; a < NW; a++) {
                z[a] = fminf(v[a] - tau, h[a]);
                zsw[n][w][a][lane] = z[a];     // wave-private: read next iter by same wave
            }
        }
        // no second barrier: zsw[n][w] is produced & consumed within wave w
    }

    if (act) {
        float m = fmaxf(fmaxf(fmaxf(z[0], z[1]), fmaxf(z[2], z[3])), z[4]);
        if (m > 0.001f) atomicAdd(&svcount, 1);
#pragma unroll
        for (int a = 0; a < NW; a++) qp3[pr * NW + a] = z[a];
    }
    __syncthreads();
    if (tid == 0) *outNumSv = (float)svcount;
}

// ---------------- W[a][d] = sum_s support[s][d] * qp3[s][a] ----------------
// 4-way s-split for ILP: wave sq covers s in [32sq, min(32sq+32,125)); LDS combine.
__global__ __launch_bounds__(256) void w_kernel(const float* __restrict__ support,
                                                const float* __restrict__ qp3,
                                                float* __restrict__ W) {
    __shared__ float q3[NS * NW];
    __shared__ float red[4 * 64 * NW];
    const int tid = threadIdx.x;
    for (int i = tid; i < NS * NW; i += 256) q3[i] = qp3[i];
    __syncthreads();
    const int ld = tid & 63;            // local d
    const int sq = tid >> 6;            // s-quarter (wave-uniform)
    const int d  = blockIdx.x * 64 + ld;
    const int s0 = sq * 32;
    const int s1 = (sq == 3) ? NS : (s0 + 32);
    float acc[NW] = {0.f, 0.f, 0.f, 0.f, 0.f};
#pragma unroll 4
    for (int s = s0; s < s1; ++s) {
        float sv = support[(size_t)s * DD + d];
#pragma unroll
        for (int a = 0; a < NW; a++) acc[a] += sv * q3[s * NW + a];
    }
    float* rr = &red[tid * NW];
#pragma unroll
    for (int a = 0; a < NW; a++) rr[a] = acc[a];
    __syncthreads();
    if (sq == 0) {
#pragma unroll
        for (int a = 0; a < NW; a++) {
            float s = red[(0 * 64 + ld) * NW + a] + red[(1 * 64 + ld) * NW + a]
                    + red[(2 * 64 + ld) * NW + a] + red[(3 * 64 + ld) * NW + a];
            W[(size_t)a * DD + d] = s;
        }
    }
}

// ---------------- logits partials: grid (q-group, d-chunk); 2 q/wave over D/4 ------
__global__ __launch_bounds__(256) void logits_partial(const float* __restrict__ query,
                                                      const float* __restrict__ W,
                                                      float* __restrict__ lp) {
    const int tid = threadIdx.x;
    const int wave = tid >> 6, lane = tid & 63;
    const int q0 = blockIdx.x * 8 + wave * 2;
    const int q1 = q0 + 1;
    const int chunk = blockIdx.y;
    const int v0 = chunk * 512;            // float4 base of this chunk (512 float4 = 2048 f)
    float a0[NW] = {0.f, 0.f, 0.f, 0.f, 0.f};
    float a1[NW] = {0.f, 0.f, 0.f, 0.f, 0.f};
    const float4* qp0 = (const float4*)(query + (size_t)q0 * DD);
    const float4* qp1 = (const float4*)(query + (size_t)q1 * DD);
    for (int it = 0; it < 8; ++it) {
        int dv = v0 + it * 64 + lane;
        float4 qv0 = qp0[dv];
        float4 qv1 = qp1[dv];
#pragma unroll
        for (int a = 0; a < NW; a++) {
            float4 wv = ((const float4*)(W + (size_t)a * DD))[dv];
            a0[a] += qv0.x * wv.x + qv0.y * wv.y + qv0.z * wv.z + qv0.w * wv.w;
            a1[a] += qv1.x * wv.x + qv1.y * wv.y + qv1.z * wv.z + qv1.w * wv.w;
        }
    }
#pragma unroll
    for (int off = 32; off; off >>= 1) {
#pragma unroll
        for (int a = 0; a < NW; a++) {
            a0[a] += __shfl_xor(a0[a], off);
            a1[a] += __shfl_xor(a1[a], off);
        }
    }
    if (lane == 0) {
        float* dst = lp + (size_t)chunk * (NQ * NW);
#pragma unroll
        for (int a = 0; a < NW; a++) dst[q0 * NW + a] = a0[a];
#pragma unroll
        for (int a = 0; a < NW; a++) dst[q1 * NW + a] = a1[a];
    }
}

// ---------------- logits finish: out = scale * sum_chunks lp ----------------
__global__ __launch_bounds__(256) void logits_finish(const float* __restrict__ lp,
                                                     const float* __restrict__ scale,
                                                     float* __restrict__ out) {
    int t = blockIdx.x * 256 + threadIdx.x;
    if (t < NQ * NW) {
        float s = lp[t] + lp[NQ * NW + t] + lp[2 * NQ * NW + t] + lp[3 * NQ * NW + t];
        out[t] = scale[0] * s;
    }
}

extern "C" void kernel_launch(void* const* d_in, const int* in_sizes, int n_in,
                              void* d_out, int out_size, void* d_ws, size_t ws_size,
                              hipStream_t stream) {
    const float* query   = (const float*)d_in[0];
    const float* support = (const float*)d_in[1];
    const int*   labels  = (const int*)d_in[2];
    const float* scale   = (const float*)d_in[5];
    float* out = (float*)d_out;
    float* ws  = (float*)d_ws;

    float* part = ws + OFF_PART;
    float* Kg   = ws + OFF_K;
    float* qp3  = ws + OFF_QP3;
    float* W    = ws + OFF_W;
    float* lp   = ws + OFF_LP;

    hipLaunchKernelGGL(gram_partial, dim3(64, 2, 2), dim3(256), 0, stream, support, part);
    hipLaunchKernelGGL(gram_reduce, dim3(62), dim3(256), 0, stream, part, Kg);
    hipLaunchKernelGGL(qp_solve, dim3(1), dim3(256), 0, stream, Kg, labels, qp3, out + NQ * NW);
    hipLaunchKernelGGL(w_kernel, dim3(DD / 64), dim3(256), 0, stream, support, qp3, W);
    hipLaunchKernelGGL(logits_partial, dim3(NQ / 8, 4), dim3(256), 0, stream, query, W, lp);
    hipLaunchKernelGGL(logits_finish, dim3((NQ * NW + 255) / 256), dim3(256), 0, stream, lp, scale, out);
}

// Round 11
// 160.159 us; speedup vs baseline: 1.8785x; 1.0532x over previous
//
#include <hip/hip_runtime.h>

#define NS   125      // n_support
#define NW   5        // n_way
#define NQ   2048
#define DD   8192
#define CREG 0.1f
#define PGD_ITERS 10

// ws float offsets
#define OFF_PART 0          // 64 * 15625 = 1,000,000 floats
#define OFF_K    1000000    // 15625
#define OFF_QP3  1016000    // 625
#define OFF_W    1017000    // 5*8192 = 40960

// ---------------- Gram partials: block = (d-chunk c, quadrant qy, qz) ----------------
__global__ __launch_bounds__(256) void gram_partial(const float* __restrict__ support,
                                                    float* __restrict__ part) {
    __shared__ __align__(16) float As[128][68];  // [d][s-local], pitch 68 (2-way reads = free)
    __shared__ __align__(16) float Bs[128][68];
    const int tid = threadIdx.x;
    const int c  = blockIdx.x;
    const int qy = blockIdx.y, qz = blockIdx.z;
    const int d0 = c * 128;
    const int sy0 = qy * 64, sz0 = qz * 64;
    for (int idx = tid; idx < 64 * 128; idx += 256) {
        int sl = idx >> 7, dj = idx & 127;
        int sa = sy0 + sl, sb = sz0 + sl;
        As[dj][sl] = (sa < NS) ? support[(size_t)sa * DD + d0 + dj] : 0.f;
        Bs[dj][sl] = (sb < NS) ? support[(size_t)sb * DD + d0 + dj] : 0.f;
    }
    __syncthreads();
    const int tx = tid & 15, ty = tid >> 4;   // 4x4 tile
    float acc[4][4];
#pragma unroll
    for (int i = 0; i < 4; i++)
#pragma unroll
        for (int j = 0; j < 4; j++) acc[i][j] = 0.f;
#pragma unroll 4
    for (int d = 0; d < 128; ++d) {
        float4 a = *(const float4*)&As[d][tx * 4];
        float4 b = *(const float4*)&Bs[d][ty * 4];
        float av[4] = {a.x, a.y, a.z, a.w};
        float bv[4] = {b.x, b.y, b.z, b.w};
#pragma unroll
        for (int i = 0; i < 4; i++)
#pragma unroll
            for (int j = 0; j < 4; j++) acc[i][j] += av[i] * bv[j];
    }
    float* dst = part + (size_t)c * (NS * NS);
#pragma unroll
    for (int i = 0; i < 4; i++) {
        int gi = sy0 + tx * 4 + i;
        if (gi >= NS) continue;
#pragma unroll
        for (int j = 0; j < 4; j++) {
            int gj = sz0 + ty * 4 + j;
            if (gj < NS) dst[gi * NS + gj] = acc[i][j];
        }
    }
}

// ---------------- Reduce partials -> K ----------------
__global__ __launch_bounds__(256) void gram_reduce(const float* __restrict__ part,
                                                   float* __restrict__ Kg) {
    int t = blockIdx.x * 256 + threadIdx.x;
    if (t < NS * NS) {
        float s = 0.f;
        for (int c = 0; c < 64; ++c) s += part[(size_t)c * (NS * NS) + t];
        Kg[t] = s;
    }
}

// ---------------- QP via PGD v3: ONE barrier/iter, wave-private z ----------------
// Wave w owns col-chunk [32w,32w+32) AND projects rows [32w,32w+32) (lanes 0-31).
// z strip is wave-private (same-wave LDS, lgkmcnt-ordered, no barrier).
// Cross-wave traffic = partial-sum slab only, fenced by the single barrier;
// WAR on red2[p] (reused at iter k+2) is ordered by barrier k+1.
__global__ __launch_bounds__(256) void qp_solve(const float* __restrict__ Kg,
                                                const int* __restrict__ labels,
                                                float* __restrict__ qp3,
                                                float* __restrict__ outNumSv) {
    __shared__ float red2[2][128 * 25];             // [parity][row*25 + w*5 + a]
    __shared__ __align__(16) float zsw[2][4][NW][32];  // [parity][wave][a][j-local]
    __shared__ float rsmax[2];
    __shared__ int svcount;

    const int tid  = threadIdx.x;
    const int w    = tid >> 6;
    const int lane = tid & 63;
    const int c0   = w * 32;
    const int r0   = lane, r1 = lane + 64;

    // K row chunks via symmetry (K==K^T), coalesced
    float kr0[32], kr1[32];
#pragma unroll
    for (int j = 0; j < 32; ++j) {
        const int col = c0 + j;
        const bool cv = (col < NS);
        kr0[j] = cv ? Kg[col * NS + r0] : 0.f;
        kr1[j] = (cv && r1 < NS) ? Kg[col * NS + r1] : 0.f;
    }
    for (int idx = tid; idx < 2 * 4 * NW * 32; idx += 256) ((float*)zsw)[idx] = 0.f;
    if (tid == 0) svcount = 0;
    float rsum0 = 0.f, rsum1 = 0.f;
#pragma unroll
    for (int j = 0; j < 32; ++j) { rsum0 += fabsf(kr0[j]); rsum1 += fabsf(kr1[j]); }
    red2[0][r0 * 25 + w * 5] = rsum0;
    red2[0][r1 * 25 + w * 5] = rsum1;
    __syncthreads();
    const int prw = w * 64 + lane;
    if (w < 2) {
        const float* rr = &red2[0][prw * 25];
        float t = (prw < NS) ? rr[0] + rr[5] + rr[10] + rr[15] : 0.f;
#pragma unroll
        for (int off = 32; off; off >>= 1) t = fmaxf(t, __shfl_xor(t, off));
        if (lane == 0) rsmax[w] = t;
    }
    __syncthreads();
    const float eta = 1.9f / (fmaxf(rsmax[0], rsmax[1]) + 1.0f);  // G = kron(K,I5)+I
    const int pr   = c0 + lane;
    const bool act = (lane < 32) && (pr < NS);
    const int lab  = act ? labels[pr] : 0;
    float z[NW] = {0.f, 0.f, 0.f, 0.f, 0.f};

    for (int it = 0; it < PGD_ITERS; ++it) {
        const int p = it & 1, n = p ^ 1;
        float acc0[NW] = {0.f, 0.f, 0.f, 0.f, 0.f};
        float acc1[NW] = {0.f, 0.f, 0.f, 0.f, 0.f};
#pragma unroll
        for (int c = 0; c < 8; ++c) {
            float4 z0 = *(const float4*)&zsw[p][w][0][4 * c];
            float4 z1 = *(const float4*)&zsw[p][w][1][4 * c];
            float4 z2 = *(const float4*)&zsw[p][w][2][4 * c];
            float4 z3 = *(const float4*)&zsw[p][w][3][4 * c];
            float4 z4 = *(const float4*)&zsw[p][w][4][4 * c];
            const float k00 = kr0[4*c], k01 = kr0[4*c+1], k02 = kr0[4*c+2], k03 = kr0[4*c+3];
            const float k10 = kr1[4*c], k11 = kr1[4*c+1], k12 = kr1[4*c+2], k13 = kr1[4*c+3];
            acc0[0] += k00*z0.x + k01*z0.y + k02*z0.z + k03*z0.w;
            acc0[1] += k00*z1.x + k01*z1.y + k02*z1.z + k03*z1.w;
            acc0[2] += k00*z2.x + k01*z2.y + k02*z2.z + k03*z2.w;
            acc0[3] += k00*z3.x + k01*z3.y + k02*z3.z + k03*z3.w;
            acc0[4] += k00*z4.x + k01*z4.y + k02*z4.z + k03*z4.w;
            acc1[0] += k10*z0.x + k11*z0.y + k12*z0.z + k13*z0.w;
            acc1[1] += k10*z1.x + k11*z1.y + k12*z1.z + k13*z1.w;
            acc1[2] += k10*z2.x + k11*z2.y + k12*z2.z + k13*z2.w;
            acc1[3] += k10*z3.x + k11*z3.y + k12*z3.z + k13*z3.w;
            acc1[4] += k10*z4.x + k11*z4.y + k12*z4.z + k13*z4.w;
        }
        {
            float* b0 = &red2[p][r0 * 25 + w * 5];
            b0[0] = acc0[0]; b0[1] = acc0[1]; b0[2] = acc0[2]; b0[3] = acc0[3]; b0[4] = acc0[4];
            float* b1 = &red2[p][r1 * 25 + w * 5];
            b1[0] = acc1[0]; b1[1] = acc1[1]; b1[2] = acc1[2]; b1[3] = acc1[3]; b1[4] = acc1[4];
        }
        __syncthreads();                       // the ONLY barrier per iteration
        if (act) {
            const float* rr = &red2[p][pr * 25];
            float v[NW], h[NW];
#pragma unroll
            for (int a = 0; a < NW; a++) {
                float kz = rr[a] + rr[5 + a] + rr[10 + a] + rr[15 + a];
                float g = kz + z[a] - ((a == lab) ? 1.f : 0.f);   // Gz + e
                v[a] = z[a] - eta * g;
                h[a] = (a == lab) ? CREG : 0.f;
            }
            float tau = fmaxf(fmaxf(fmaxf(v[0], v[1]), fmaxf(v[2], v[3])), v[4]);
#pragma unroll
            for (int nn = 0; nn < 7; ++nn) {
                float g = 0.f, nf = 0.f;
#pragma unroll
                for (int a = 0; a < NW; a++) {
                    float d = v[a] - tau;
                    bool fr = (d <= h[a]);
                    g += fr ? d : h[a];
                    nf += fr ? 1.f : 0.f;
                }
                tau += g / nf;
            }
#pragma unroll
            for (int a = 0; a < NW; a++) {
                z[a] = fminf(v[a] - tau, h[a]);
                zsw[n][w][a][lane] = z[a];
            }
        }
    }

    if (act) {
        float m = fmaxf(fmaxf(fmaxf(z[0], z[1]), fmaxf(z[2], z[3])), z[4]);
        if (m > 0.001f) atomicAdd(&svcount, 1);
#pragma unroll
        for (int a = 0; a < NW; a++) qp3[pr * NW + a] = z[a];
    }
    __syncthreads();
    if (tid == 0) *outNumSv = (float)svcount;
}

// ---------------- W[a][d] = sum_s support[s][d] * qp3[s][a] ----------------
__global__ __launch_bounds__(256) void w_kernel(const float* __restrict__ support,
                                                const float* __restrict__ qp3,
                                                float* __restrict__ W) {
    __shared__ float q3[NS * NW];
    __shared__ float red[4 * 64 * NW];
    const int tid = threadIdx.x;
    for (int i = tid; i < NS * NW; i += 256) q3[i] = qp3[i];
    __syncthreads();
    const int ld = tid & 63;            // local d
    const int sq = tid >> 6;            // s-quarter (wave-uniform)
    const int d  = blockIdx.x * 64 + ld;
    const int s0 = sq * 32;
    const int s1 = (sq == 3) ? NS : (s0 + 32);
    float acc[NW] = {0.f, 0.f, 0.f, 0.f, 0.f};
#pragma unroll 4
    for (int s = s0; s < s1; ++s) {
        float sv = support[(size_t)s * DD + d];
#pragma unroll
        for (int a = 0; a < NW; a++) acc[a] += sv * q3[s * NW + a];
    }
    float* rr = &red[tid * NW];
#pragma unroll
    for (int a = 0; a < NW; a++) rr[a] = acc[a];
    __syncthreads();
    if (sq == 0) {
#pragma unroll
        for (int a = 0; a < NW; a++) {
            float s = red[(0 * 64 + ld) * NW + a] + red[(1 * 64 + ld) * NW + a]
                    + red[(2 * 64 + ld) * NW + a] + red[(3 * 64 + ld) * NW + a];
            W[(size_t)a * DD + d] = s;
        }
    }
}

// ---------------- logits single kernel: in-block d-split, LDS combine ----------------
// grid NQ/2 = 1024 blocks; wave w covers d-chunk [512w, 512w+512) float4s of 2 queries.
// No cross-block coupling -> no fences; one barrier for the 160 B combine.
__global__ __launch_bounds__(256) void logits_kernel(const float* __restrict__ query,
                                                     const float* __restrict__ W,
                                                     const float* __restrict__ scale,
                                                     float* __restrict__ out) {
    __shared__ float red[4][2][NW];
    const int tid = threadIdx.x;
    const int wave = tid >> 6, lane = tid & 63;
    const int q0 = blockIdx.x * 2;
    const int v0 = wave * 512;             // this wave's float4 base (512 float4 = 2048 f)
    float a0[NW] = {0.f, 0.f, 0.f, 0.f, 0.f};
    float a1[NW] = {0.f, 0.f, 0.f, 0.f, 0.f};
    const float4* qp0 = (const float4*)(query + (size_t)q0 * DD);
    const float4* qp1 = (const float4*)(query + (size_t)(q0 + 1) * DD);
    for (int it = 0; it < 8; ++it) {
        int dv = v0 + it * 64 + lane;
        float4 qv0 = qp0[dv];
        float4 qv1 = qp1[dv];
#pragma unroll
        for (int a = 0; a < NW; a++) {
            float4 wv = ((const float4*)(W + (size_t)a * DD))[dv];
            a0[a] += qv0.x * wv.x + qv0.y * wv.y + qv0.z * wv.z + qv0.w * wv.w;
            a1[a] += qv1.x * wv.x + qv1.y * wv.y + qv1.z * wv.z + qv1.w * wv.w;
        }
    }
#pragma unroll
    for (int off = 32; off; off >>= 1) {
#pragma unroll
        for (int a = 0; a < NW; a++) {
            a0[a] += __shfl_xor(a0[a], off);
            a1[a] += __shfl_xor(a1[a], off);
        }
    }
    if (lane == 0) {
#pragma unroll
        for (int a = 0; a < NW; a++) { red[wave][0][a] = a0[a]; red[wave][1][a] = a1[a]; }
    }
    __syncthreads();
    if (tid < 2 * NW) {
        const int ql = tid / NW, a = tid % NW;
        float s = red[0][ql][a] + red[1][ql][a] + red[2][ql][a] + red[3][ql][a];
        out[(q0 + ql) * NW + a] = scale[0] * s;
    }
}

extern "C" void kernel_launch(void* const* d_in, const int* in_sizes, int n_in,
                              void* d_out, int out_size, void* d_ws, size_t ws_size,
                              hipStream_t stream) {
    const float* query   = (const float*)d_in[0];
    const float* support = (const float*)d_in[1];
    const int*   labels  = (const int*)d_in[2];
    const float* scale   = (const float*)d_in[5];
    float* out = (float*)d_out;
    float* ws  = (float*)d_ws;

    float* part = ws + OFF_PART;
    float* Kg   = ws + OFF_K;
    float* qp3  = ws + OFF_QP3;
    float* W    = ws + OFF_W;

    hipLaunchKernelGGL(gram_partial, dim3(64, 2, 2), dim3(256), 0, stream, support, part);
    hipLaunchKernelGGL(gram_reduce, dim3(62), dim3(256), 0, stream, part, Kg);
    hipLaunchKernelGGL(qp_solve, dim3(1), dim3(256), 0, stream, Kg, labels, qp3, out + NQ * NW);
    hipLaunchKernelGGL(w_kernel, dim3(DD / 64), dim3(256), 0, stream, support, qp3, W);
    hipLaunchKernelGGL(logits_kernel, dim3(NQ / 2), dim3(256), 0, stream, query, W, scale, out);
}